// Round 5
// baseline (1118.586 us; speedup 1.0000x reference)
//
#include <hip/hip_runtime.h>

typedef unsigned short u16;
typedef __attribute__((ext_vector_type(8))) short bf16x8;   // MFMA A/B operand (8 bf16 = 4 VGPR)
typedef __attribute__((ext_vector_type(8))) unsigned short u16x8;
typedef __attribute__((ext_vector_type(4))) float f32x4;    // MFMA C/D operand

#define HIDDEN 4096
#define NH 32
#define NKV 8
#define HD 128
#define BB 2
#define SS 2048
#define TOK (BB * SS)   // 4096
#define MAXPOS 4096
#define NQKV 6144        // 4096 + 1024 + 1024

__device__ __forceinline__ u16 f2bf(float f) {
  unsigned u = __float_as_uint(f);
  u += 0x7FFFu + ((u >> 16) & 1u);   // RNE
  return (u16)(u >> 16);
}
__device__ __forceinline__ float bf2f(u16 u) {
  return __uint_as_float(((unsigned)u) << 16);
}

__device__ __forceinline__ void gload_lds16(const u16* g, u16* l) {
  __builtin_amdgcn_global_load_lds(
      (const __attribute__((address_space(1))) unsigned int*)g,
      (__attribute__((address_space(3))) unsigned int*)l, 16, 0, 0);
}

// XOR-swizzled LDS addressing (T2): same involution on write and read.
__device__ __forceinline__ u16* swzp(u16* base, int row, int col, int stride) {
  int off = (row * stride + col) * 2;
  off ^= (row & 7) << 4;
  return (u16*)((char*)base + off);
}
__device__ __forceinline__ const u16* swzc(const u16* base, int row, int col, int stride) {
  int off = (row * stride + col) * 2;
  off ^= (row & 7) << 4;
  return (const u16*)((const char*)base + off);
}

// ---------------- conversion kernels ----------------

__global__ void conv_bf16(const float* __restrict__ X, u16* __restrict__ Y, int n8) {
  int i = blockIdx.x * 256 + threadIdx.x;
  if (i >= n8) return;
  const float4* p = (const float4*)X;
  float4 a = p[2 * (long)i], b = p[2 * (long)i + 1];
  u16x8 o;
  o[0] = f2bf(a.x); o[1] = f2bf(a.y); o[2] = f2bf(a.z); o[3] = f2bf(a.w);
  o[4] = f2bf(b.x); o[5] = f2bf(b.y); o[6] = f2bf(b.z); o[7] = f2bf(b.w);
  *(u16x8*)&Y[(long)i * 8] = o;
}

// W [K][N] fp32  ->  Wt [N][K] bf16
__global__ __launch_bounds__(256) void conv_transpose(const float* __restrict__ W,
                                                      u16* __restrict__ Wt,
                                                      int K, int N) {
  __shared__ float tile[64][65];
  const int n0 = blockIdx.x * 64, k0 = blockIdx.y * 64;
  const int t = threadIdx.x;
  const int r = t >> 4, c4 = (t & 15) * 4;
#pragma unroll
  for (int i = 0; i < 4; i++) {
    float4 v = *(const float4*)&W[(long)(k0 + r + i * 16) * N + n0 + c4];
    tile[r + i * 16][c4 + 0] = v.x;
    tile[r + i * 16][c4 + 1] = v.y;
    tile[r + i * 16][c4 + 2] = v.z;
    tile[r + i * 16][c4 + 3] = v.w;
  }
  __syncthreads();
#pragma unroll
  for (int i = 0; i < 4; i++) {
    int n = r + i * 16;
    ushort4 o;
    o.x = f2bf(tile[c4 + 0][n]);
    o.y = f2bf(tile[c4 + 1][n]);
    o.z = f2bf(tile[c4 + 2][n]);
    o.w = f2bf(tile[c4 + 3][n]);
    *(ushort4*)&Wt[(long)(n0 + n) * K + k0 + c4] = o;
  }
}

// ---------------- RoPE ----------------

__global__ void rope_table(float* __restrict__ st, float* __restrict__ ct) {
  int i = blockIdx.x * 256 + threadIdx.x;   // MAXPOS*64
  int pos = i >> 6, j = i & 63;
  float inv = exp2f(-(float)(2 * j) * (13.287712379549449f / 128.f));
  float a = (float)pos * inv;
  st[i] = sinf(a);
  ct[i] = cosf(a);
}

// scale folds the attention 1/sqrt(HD) into Q at RoPE time (1.0 for K).
__global__ void rope_apply(u16* __restrict__ T, const int* __restrict__ pid,
                           const float* __restrict__ st, const float* __restrict__ ct,
                           int nh, int total, float scale) {
  int i = blockIdx.x * 256 + threadIdx.x;
  if (i >= total) return;
  int j = i & 63;
  int rest = i >> 6;
  int h = rest % nh;
  int tok = rest / nh;
  int pos = pid[tok];
  long base = ((long)tok * nh + h) * 128;
  float c = ct[pos * 64 + j], s = st[pos * 64 + j];
  float a = bf2f(T[base + j]), b = bf2f(T[base + 64 + j]);
  T[base + j]      = f2bf((a * c - b * s) * scale);
  T[base + 64 + j] = f2bf((b * c + a * s) * scale);
}

// per-64-key-tile padding-mask flags: mf[b*(SS/64)+t] = any(amask<=0) in tile
__global__ void mask_flags(const float* __restrict__ amask, int* __restrict__ mf) {
  int i = threadIdx.x;                 // BB * SS/64 = 64 flags, one block
  if (i >= BB * (SS / 64)) return;
  int b = i / (SS / 64), tt = i % (SS / 64);
  int any = 0;
  for (int k = 0; k < 64; k++) any |= (amask[b * SS + tt * 64 + k] <= 0.f) ? 1 : 0;
  mf[i] = any;
}

// V [B,S,NKV,HD] -> Vt [B,NKV,HD,S]
__global__ __launch_bounds__(256) void vtrans(const u16* __restrict__ V, u16* __restrict__ Vt) {
  __shared__ u16 tile[64][68];
  const int s0 = blockIdx.x * 64, d0 = blockIdx.y * 64;
  const int bk = blockIdx.z;            // b*NKV + kvh
  const int b = bk >> 3, kvh = bk & 7;
  const int t = threadIdx.x;
  const int r = t >> 4, c4 = (t & 15) * 4;
#pragma unroll
  for (int i = 0; i < 4; i++) {
    int s = s0 + r + i * 16;
    ushort4 v = *(const ushort4*)&V[(((long)b * SS + s) * NKV + kvh) * HD + d0 + c4];
    tile[r + i * 16][c4 + 0] = v.x;
    tile[r + i * 16][c4 + 1] = v.y;
    tile[r + i * 16][c4 + 2] = v.z;
    tile[r + i * 16][c4 + 3] = v.w;
  }
  __syncthreads();
#pragma unroll
  for (int i = 0; i < 4; i++) {
    int d = r + i * 16;
    ushort4 o;
    o.x = tile[c4 + 0][d];
    o.y = tile[c4 + 1][d];
    o.z = tile[c4 + 2][d];
    o.w = tile[c4 + 3][d];
    *(ushort4*)&Vt[(((long)bk) * HD + d0 + d) * SS + s0 + c4] = o;
  }
}

// ---------------- GEMM core (m97 structure): 128x128 tile, BK=64 ----------------
// Computes acc for C-tile (brow,bcol); caller provides epilogue.

#define GEMM_BODY(A, Bt, K)                                                        \
  __shared__ u16 As[128 * 64];                                                     \
  __shared__ u16 Bs[128 * 64];                                                     \
  const int t = threadIdx.x;                                                       \
  const int lane = t & 63, wv = t >> 6;                                            \
  const int wr = wv >> 1, wc = wv & 1;                                             \
  const int fr = lane & 15, fq = lane >> 4;                                        \
  f32x4 acc[4][4] = {};                                                            \
  const int rs = wv * 8 + (lane >> 3);                                             \
  const int cs = (lane & 7) * 8;                                                   \
  const u16* Ag = A + (brow + rs) * (long)(K) + cs;                                \
  const u16* Bg = Bt + (bcol + rs) * (long)(K) + cs;                               \
  u16* Al = &As[rs * 64 + cs];                                                     \
  u16* Bl = &Bs[rs * 64 + cs];                                                     \
  for (int k0 = 0; k0 < (K); k0 += 64) {                                           \
    _Pragma("unroll") for (int i = 0; i < 4; i++) {                                \
      gload_lds16(Ag + (long)i * 32 * (K) + k0, Al + i * 32 * 64);                 \
      gload_lds16(Bg + (long)i * 32 * (K) + k0, Bl + i * 32 * 64);                 \
    }                                                                              \
    __syncthreads();                                                               \
    _Pragma("unroll") for (int kk = 0; kk < 2; kk++) {                             \
      bf16x8 af[4], bfr[4];                                                        \
      _Pragma("unroll") for (int m = 0; m < 4; m++)                                \
        af[m] = *(const bf16x8*)&As[(wr * 64 + m * 16 + fr) * 64 + kk * 32 + fq * 8]; \
      _Pragma("unroll") for (int n = 0; n < 4; n++)                                \
        bfr[n] = *(const bf16x8*)&Bs[(wc * 64 + n * 16 + fr) * 64 + kk * 32 + fq * 8]; \
      _Pragma("unroll") for (int m = 0; m < 4; m++)                                \
        _Pragma("unroll") for (int n = 0; n < 4; n++)                              \
          acc[m][n] = __builtin_amdgcn_mfma_f32_16x16x32_bf16(af[m], bfr[n], acc[m][n], 0, 0, 0); \
    }                                                                              \
    __syncthreads();                                                               \
  }

// Fused QKV projection: Bt = [Wq^T | Wk^T | Wv^T] as [6144][4096].
// Epilogue routes cols [0,4096)->Qb, [4096,5120)->Kb, [5120,6144)->Vb.
__global__ __launch_bounds__(256) void gemm_qkv(const u16* __restrict__ A,
                                                const u16* __restrict__ Bt,
                                                u16* __restrict__ Qb,
                                                u16* __restrict__ Kb,
                                                u16* __restrict__ Vb) {
  const long brow = (long)blockIdx.y * 128, bcol = (long)blockIdx.x * 128;
  GEMM_BODY(A, Bt, HIDDEN)
  u16* dst;
  long nst, cb;
  if (bcol < 4096)      { dst = Qb; nst = 4096; cb = bcol; }
  else if (bcol < 5120) { dst = Kb; nst = 1024; cb = bcol - 4096; }
  else                  { dst = Vb; nst = 1024; cb = bcol - 5120; }
#pragma unroll
  for (int m = 0; m < 4; m++)
#pragma unroll
    for (int j = 0; j < 4; j++) {
      long row = brow + wr * 64 + m * 16 + fq * 4 + j;
#pragma unroll
      for (int n = 0; n < 4; n++)
        dst[row * nst + cb + wc * 64 + n * 16 + fr] = f2bf(acc[m][n][j]);
    }
}

// Output projection: C fp32 [M][N]
__global__ __launch_bounds__(256) void gemm_out(const u16* __restrict__ A,
                                                const u16* __restrict__ Bt,
                                                float* __restrict__ C) {
  const long brow = (long)blockIdx.y * 128, bcol = (long)blockIdx.x * 128;
  GEMM_BODY(A, Bt, HIDDEN)
#pragma unroll
  for (int m = 0; m < 4; m++)
#pragma unroll
    for (int j = 0; j < 4; j++) {
      long row = brow + wr * 64 + m * 16 + fq * 4 + j;
#pragma unroll
      for (int n = 0; n < 4; n++)
        C[row * HIDDEN + bcol + wc * 64 + n * 16 + fr] = acc[m][n][j];
    }
}

// ---------------- flash attention (causal, GQA) ----------------
// grid (S/64, NH, B), 256 threads = 4 waves, each owns 16 q-rows.
// T2 swizzled LDS (40KB, 4 blocks/CU), T14 depth-2 reg prefetch, T13 defer-max,
// T5 setprio, wave-uniform mask skipping (mask_flags), pre-scaled Q.

__global__ __launch_bounds__(256) void attn_fwd(const u16* __restrict__ Q,
                                                const u16* __restrict__ K,
                                                const u16* __restrict__ Vt,
                                                const float* __restrict__ amask,
                                                const int* __restrict__ mflag,
                                                u16* __restrict__ O) {
  const int b = blockIdx.z, h = blockIdx.y;
  const int qi = gridDim.x - 1 - blockIdx.x;   // heavy (high-qb) blocks first (LPT)
  const int qb = qi * 64;
  const int kvh = h >> 2;
  const int t = threadIdx.x, lane = t & 63, w = t >> 6;
  const int fr = lane & 15, fq = lane >> 4;

  __shared__ u16 KlA[64 * 128];       // [key][d],   swizzled, 16KB
  __shared__ u16 VlA[128 * 64];       // [d][key],   swizzled, 16KB
  __shared__ u16 PlA[4][16 * 64];     // per-wave [qrow][key], swizzled, 8KB

  bf16x8 qf[4];
  {
    const int qrow = qb + w * 16 + fr;
    const long qbase = (((long)b * SS + qrow) * NH + h) * HD;
#pragma unroll
    for (int kk = 0; kk < 4; kk++)
      qf[kk] = *(const bf16x8*)&Q[qbase + kk * 32 + fq * 8];
  }

  const u16* Kh = K + (long)b * SS * NKV * HD + (long)kvh * HD;
  const u16* Vh = Vt + ((long)b * NKV + kvh) * (long)HD * SS;
  const float* Mh = amask + (long)b * SS;
  const int* Mf = mflag + b * (SS / 64);
  u16* Plw = PlA[w];

  const int kst = t >> 4, kcol = (t & 15) * 8;   // K: 64 rows x 128 cols
  const int vst = t >> 3, vcol = (t & 7) * 8;    // V: 128 rows x 64 cols

  bf16x8 kreg[4], vreg[4];
  auto load_tile = [&](int kv0) {
#pragma unroll
    for (int i = 0; i < 4; i++)
      kreg[i] = *(const bf16x8*)&Kh[(long)(kv0 + kst + i * 16) * (NKV * HD) + kcol];
#pragma unroll
    for (int i = 0; i < 4; i++)
      vreg[i] = *(const bf16x8*)&Vh[(long)(vst + i * 32) * SS + kv0 + vcol];
  };
  auto write_tile = [&]() {
#pragma unroll
    for (int i = 0; i < 4; i++)
      *(bf16x8*)swzp(KlA, kst + i * 16, kcol, 128) = kreg[i];
#pragma unroll
    for (int i = 0; i < 4; i++)
      *(bf16x8*)swzp(VlA, vst + i * 32, vcol, 64) = vreg[i];
  };

  f32x4 oacc[8] = {};
  float mrow[4], lrow[4];
#pragma unroll
  for (int j = 0; j < 4; j++) { mrow[j] = -1e30f; lrow[j] = 0.f; }
  const int qr0 = qb + w * 16 + fq * 4;
  const float L2E = 1.4426950408889634f;

  const int ntiles = qi + 1;
  load_tile(0);
  write_tile();
  __syncthreads();
  if (ntiles > 1) load_tile(64);

  for (int kvt = 0; kvt < ntiles; kvt++) {
    const int kv0 = kvt * 64;

    // ---- S = Q K^T ----
    f32x4 sacc[4] = {};
    __builtin_amdgcn_s_setprio(1);
#pragma unroll
    for (int n = 0; n < 4; n++)
#pragma unroll
      for (int kk = 0; kk < 4; kk++) {
        bf16x8 kf = *(const bf16x8*)swzc(KlA, n * 16 + fr, kk * 32 + fq * 8, 128);
        sacc[n] = __builtin_amdgcn_mfma_f32_16x16x32_bf16(qf[kk], kf, sacc[n], 0, 0, 0);
      }
    __builtin_amdgcn_s_setprio(0);

    // ---- masking (wave-uniform branches; rare paths) ----
    if (kvt == qi) {                      // causal diagonal tile only
#pragma unroll
      for (int n = 0; n < 4; n++) {
        const int key = kv0 + n * 16 + fr;
#pragma unroll
        for (int j = 0; j < 4; j++)
          if (key > qr0 + j) sacc[n][j] = -1e30f;
      }
    }
    if (Mf[kvt]) {                        // padding mask present in this tile
      float mk[4];
#pragma unroll
      for (int n = 0; n < 4; n++) mk[n] = Mh[kv0 + n * 16 + fr];
#pragma unroll
      for (int n = 0; n < 4; n++)
#pragma unroll
        for (int j = 0; j < 4; j++)
          if (mk[n] <= 0.f) sacc[n][j] = -1e30f;
    }

    // ---- online softmax with defer-max (T13, THR=8) ----
    float pm[4];
    bool need = false;
#pragma unroll
    for (int j = 0; j < 4; j++) {
      float mx = fmaxf(fmaxf(sacc[0][j], sacc[1][j]), fmaxf(sacc[2][j], sacc[3][j]));
#pragma unroll
      for (int d = 1; d < 16; d <<= 1) mx = fmaxf(mx, __shfl_xor(mx, d, 64));
      pm[j] = mx;
      need = need || (mx > mrow[j] + 8.f);
    }
    if (__any(need)) {
#pragma unroll
      for (int j = 0; j < 4; j++) {
        float mnew = fmaxf(mrow[j], pm[j]);
        float alpha = exp2f((mrow[j] - mnew) * L2E);
        lrow[j] *= alpha;
        mrow[j] = mnew;
#pragma unroll
        for (int no = 0; no < 8; no++) oacc[no][j] *= alpha;
      }
    }
    // exp + P->LDS first (ds_writes retire under the sum reduction)
#pragma unroll
    for (int j = 0; j < 4; j++)
#pragma unroll
      for (int n = 0; n < 4; n++)
        sacc[n][j] = exp2f((sacc[n][j] - mrow[j]) * L2E);
#pragma unroll
    for (int n = 0; n < 4; n++)
#pragma unroll
      for (int j = 0; j < 4; j++)
        *swzp(Plw, fq * 4 + j, n * 16 + fr, 64) = f2bf(sacc[n][j]);
#pragma unroll
    for (int j = 0; j < 4; j++) {
      float sum = sacc[0][j] + sacc[1][j] + sacc[2][j] + sacc[3][j];
#pragma unroll
      for (int d = 1; d < 16; d <<= 1) sum += __shfl_xor(sum, d, 64);
      lrow[j] += sum;
    }

    // ---- O += P V ----
    __builtin_amdgcn_s_setprio(1);
#pragma unroll
    for (int kk = 0; kk < 2; kk++) {
      bf16x8 pf = *(const bf16x8*)swzc(Plw, fr, kk * 32 + fq * 8, 64);
#pragma unroll
      for (int no = 0; no < 8; no++) {
        bf16x8 vf = *(const bf16x8*)swzc(VlA, no * 16 + fr, kk * 32 + fq * 8, 64);
        oacc[no] = __builtin_amdgcn_mfma_f32_16x16x32_bf16(pf, vf, oacc[no], 0, 0, 0);
      }
    }
    __builtin_amdgcn_s_setprio(0);

    __syncthreads();               // all waves done reading Kl/Vl tile t
    if (kvt + 1 < ntiles) {
      write_tile();                // tile t+1 regs -> LDS
      if (kvt + 2 < ntiles) load_tile((kvt + 2) * 64);  // prefetch t+2
      __syncthreads();             // staging visible
    }
  }

  // ---- epilogue ----
#pragma unroll
  for (int j = 0; j < 4; j++) {
    const int row = qb + w * 16 + fq * 4 + j;
    const float inv = 1.0f / lrow[j];
    const long obase = (((long)b * SS + row) * NH + h) * HD;
#pragma unroll
    for (int no = 0; no < 8; no++)
      O[obase + no * 16 + fr] = f2bf(oacc[no][j] * inv);
  }
}

// ---------------- launch ----------------

extern "C" void kernel_launch(void* const* d_in, const int* in_sizes, int n_in,
                              void* d_out, int out_size, void* d_ws, size_t ws_size,
                              hipStream_t stream) {
  const float* hs    = (const float*)d_in[0];
  const float* amask = (const float*)d_in[1];
  const int*   pid   = (const int*)d_in[2];
  const float* Wq    = (const float*)d_in[3];
  const float* Wk    = (const float*)d_in[4];
  const float* Wv    = (const float*)d_in[5];
  const float* Wo    = (const float*)d_in[6];
  float* out = (float*)d_out;

  char* ws = (char*)d_ws;
  const size_t MB = 1024ull * 1024ull;
  u16* Xb    = (u16*)(ws + 0);         // 32MB, later reused as attention output
  u16* Wqkvt = (u16*)(ws + 32 * MB);   // 48MB: [Wq^T|Wk^T|Wv^T] as [6144][4096]
  u16* Wot   = (u16*)(ws + 80 * MB);   // 32MB
  u16* Qb    = (u16*)(ws + 112 * MB);  // 32MB
  u16* Kb    = (u16*)(ws + 144 * MB);  // 8MB
  u16* Vb    = (u16*)(ws + 152 * MB);  // 8MB
  u16* Vtb   = (u16*)(ws + 160 * MB);  // 8MB
  float* st  = (float*)(ws + 168 * MB);// 1MB
  float* ct  = (float*)(ws + 169 * MB);// 1MB
  int* mf    = (int*)(ws + 170 * MB);  // 256B
  u16* Ab = Xb;                        // alias: Xb dead after QKV GEMM

  rope_table<<<(MAXPOS * 64) / 256, 256, 0, stream>>>(st, ct);
  mask_flags<<<1, 64, 0, stream>>>(amask, mf);
  conv_bf16<<<(TOK * HIDDEN / 8) / 256, 256, 0, stream>>>(hs, Xb, TOK * HIDDEN / 8);
  conv_transpose<<<dim3(HIDDEN / 64, HIDDEN / 64), 256, 0, stream>>>(Wq, Wqkvt, HIDDEN, HIDDEN);
  conv_transpose<<<dim3(1024 / 64, HIDDEN / 64), 256, 0, stream>>>(Wk, Wqkvt + 4096ull * 4096, HIDDEN, 1024);
  conv_transpose<<<dim3(1024 / 64, HIDDEN / 64), 256, 0, stream>>>(Wv, Wqkvt + 5120ull * 4096, HIDDEN, 1024);
  conv_transpose<<<dim3(HIDDEN / 64, HIDDEN / 64), 256, 0, stream>>>(Wo, Wot, HIDDEN, HIDDEN);

  gemm_qkv<<<dim3(NQKV / 128, TOK / 128), 256, 0, stream>>>(Xb, Wqkvt, Qb, Kb, Vb);

  const float qscale = 0.08838834764831845f;  // 1/sqrt(HD)
  rope_apply<<<(TOK * NH * 64) / 256, 256, 0, stream>>>(Qb, pid, st, ct, NH, TOK * NH * 64, qscale);
  rope_apply<<<(TOK * NKV * 64) / 256, 256, 0, stream>>>(Kb, pid, st, ct, NKV, TOK * NKV * 64, 1.0f);

  vtrans<<<dim3(SS / 64, HD / 64, BB * NKV), 256, 0, stream>>>(Vb, Vtb);

  attn_fwd<<<dim3(SS / 64, NH, BB), 256, 0, stream>>>(Qb, Kb, Vtb, amask, mf, Ab);

  gemm_out<<<dim3(HIDDEN / 128, TOK / 128), 256, 0, stream>>>(Ab, Wot, out);
}

// Round 6
// 923.876 us; speedup vs baseline: 1.2108x; 1.2108x over previous
//
#include <hip/hip_runtime.h>

typedef unsigned short u16;
typedef __attribute__((ext_vector_type(8))) short bf16x8;   // MFMA A/B operand (8 bf16 = 4 VGPR)
typedef __attribute__((ext_vector_type(8))) unsigned short u16x8;
typedef __attribute__((ext_vector_type(4))) float f32x4;    // MFMA C/D operand

#define HIDDEN 4096
#define NH 32
#define NKV 8
#define HD 128
#define BB 2
#define SS 2048
#define TOK (BB * SS)   // 4096
#define MAXPOS 4096
#define NQKV 6144        // 4096 + 1024 + 1024

__device__ __forceinline__ u16 f2bf(float f) {
  unsigned u = __float_as_uint(f);
  u += 0x7FFFu + ((u >> 16) & 1u);   // RNE
  return (u16)(u >> 16);
}
__device__ __forceinline__ float bf2f(u16 u) {
  return __uint_as_float(((unsigned)u) << 16);
}

__device__ __forceinline__ void gload_lds16(const u16* g, u16* l) {
  __builtin_amdgcn_global_load_lds(
      (const __attribute__((address_space(1))) unsigned int*)g,
      (__attribute__((address_space(3))) unsigned int*)l, 16, 0, 0);
}

// XOR-swizzled LDS addressing (T2): same involution on write and read.
__device__ __forceinline__ u16* swzp(u16* base, int row, int col, int stride) {
  int off = (row * stride + col) * 2;
  off ^= (row & 7) << 4;
  return (u16*)((char*)base + off);
}
__device__ __forceinline__ const u16* swzc(const u16* base, int row, int col, int stride) {
  int off = (row * stride + col) * 2;
  off ^= (row & 7) << 4;
  return (const u16*)((const char*)base + off);
}

// ---------------- conversion kernels ----------------

__global__ void conv_bf16(const float* __restrict__ X, u16* __restrict__ Y, int n8) {
  int i = blockIdx.x * 256 + threadIdx.x;
  if (i >= n8) return;
  const float4* p = (const float4*)X;
  float4 a = p[2 * (long)i], b = p[2 * (long)i + 1];
  u16x8 o;
  o[0] = f2bf(a.x); o[1] = f2bf(a.y); o[2] = f2bf(a.z); o[3] = f2bf(a.w);
  o[4] = f2bf(b.x); o[5] = f2bf(b.y); o[6] = f2bf(b.z); o[7] = f2bf(b.w);
  *(u16x8*)&Y[(long)i * 8] = o;
}

// W [K][N] fp32  ->  Wt [N][K] bf16
__global__ __launch_bounds__(256) void conv_transpose(const float* __restrict__ W,
                                                      u16* __restrict__ Wt,
                                                      int K, int N) {
  __shared__ float tile[64][65];
  const int n0 = blockIdx.x * 64, k0 = blockIdx.y * 64;
  const int t = threadIdx.x;
  const int r = t >> 4, c4 = (t & 15) * 4;
#pragma unroll
  for (int i = 0; i < 4; i++) {
    float4 v = *(const float4*)&W[(long)(k0 + r + i * 16) * N + n0 + c4];
    tile[r + i * 16][c4 + 0] = v.x;
    tile[r + i * 16][c4 + 1] = v.y;
    tile[r + i * 16][c4 + 2] = v.z;
    tile[r + i * 16][c4 + 3] = v.w;
  }
  __syncthreads();
#pragma unroll
  for (int i = 0; i < 4; i++) {
    int n = r + i * 16;
    ushort4 o;
    o.x = f2bf(tile[c4 + 0][n]);
    o.y = f2bf(tile[c4 + 1][n]);
    o.z = f2bf(tile[c4 + 2][n]);
    o.w = f2bf(tile[c4 + 3][n]);
    *(ushort4*)&Wt[(long)(n0 + n) * K + k0 + c4] = o;
  }
}

// ---------------- RoPE ----------------

__global__ void rope_table(float* __restrict__ st, float* __restrict__ ct) {
  int i = blockIdx.x * 256 + threadIdx.x;   // MAXPOS*64
  int pos = i >> 6, j = i & 63;
  float inv = exp2f(-(float)(2 * j) * (13.287712379549449f / 128.f));
  float a = (float)pos * inv;
  st[i] = sinf(a);
  ct[i] = cosf(a);
}

// scale folds the attention 1/sqrt(HD) into Q at RoPE time (1.0 for K).
__global__ void rope_apply(u16* __restrict__ T, const int* __restrict__ pid,
                           const float* __restrict__ st, const float* __restrict__ ct,
                           int nh, int total, float scale) {
  int i = blockIdx.x * 256 + threadIdx.x;
  if (i >= total) return;
  int j = i & 63;
  int rest = i >> 6;
  int h = rest % nh;
  int tok = rest / nh;
  int pos = pid[tok];
  long base = ((long)tok * nh + h) * 128;
  float c = ct[pos * 64 + j], s = st[pos * 64 + j];
  float a = bf2f(T[base + j]), b = bf2f(T[base + 64 + j]);
  T[base + j]      = f2bf((a * c - b * s) * scale);
  T[base + 64 + j] = f2bf((b * c + a * s) * scale);
}

// V [B,S,NKV,HD] -> Vt [B,NKV,HD,S]
__global__ __launch_bounds__(256) void vtrans(const u16* __restrict__ V, u16* __restrict__ Vt) {
  __shared__ u16 tile[64][68];
  const int s0 = blockIdx.x * 64, d0 = blockIdx.y * 64;
  const int bk = blockIdx.z;            // b*NKV + kvh
  const int b = bk >> 3, kvh = bk & 7;
  const int t = threadIdx.x;
  const int r = t >> 4, c4 = (t & 15) * 4;
#pragma unroll
  for (int i = 0; i < 4; i++) {
    int s = s0 + r + i * 16;
    ushort4 v = *(const ushort4*)&V[(((long)b * SS + s) * NKV + kvh) * HD + d0 + c4];
    tile[r + i * 16][c4 + 0] = v.x;
    tile[r + i * 16][c4 + 1] = v.y;
    tile[r + i * 16][c4 + 2] = v.z;
    tile[r + i * 16][c4 + 3] = v.w;
  }
  __syncthreads();
#pragma unroll
  for (int i = 0; i < 4; i++) {
    int d = r + i * 16;
    ushort4 o;
    o.x = tile[c4 + 0][d];
    o.y = tile[c4 + 1][d];
    o.z = tile[c4 + 2][d];
    o.w = tile[c4 + 3][d];
    *(ushort4*)&Vt[(((long)bk) * HD + d0 + d) * SS + s0 + c4] = o;
  }
}

// ---------------- GEMM core (m97 structure): 128x128 tile, BK=64 ----------------

#define GEMM_BODY(A, Bt, K)                                                        \
  __shared__ u16 As[128 * 64];                                                     \
  __shared__ u16 Bs[128 * 64];                                                     \
  const int t = threadIdx.x;                                                       \
  const int lane = t & 63, wv = t >> 6;                                            \
  const int wr = wv >> 1, wc = wv & 1;                                             \
  const int fr = lane & 15, fq = lane >> 4;                                        \
  f32x4 acc[4][4] = {};                                                            \
  const int rs = wv * 8 + (lane >> 3);                                             \
  const int cs = (lane & 7) * 8;                                                   \
  const u16* Ag = A + (brow + rs) * (long)(K) + cs;                                \
  const u16* Bg = Bt + (bcol + rs) * (long)(K) + cs;                               \
  u16* Al = &As[rs * 64 + cs];                                                     \
  u16* Bl = &Bs[rs * 64 + cs];                                                     \
  for (int k0 = 0; k0 < (K); k0 += 64) {                                           \
    _Pragma("unroll") for (int i = 0; i < 4; i++) {                                \
      gload_lds16(Ag + (long)i * 32 * (K) + k0, Al + i * 32 * 64);                 \
      gload_lds16(Bg + (long)i * 32 * (K) + k0, Bl + i * 32 * 64);                 \
    }                                                                              \
    __syncthreads();                                                               \
    _Pragma("unroll") for (int kk = 0; kk < 2; kk++) {                             \
      bf16x8 af[4], bfr[4];                                                        \
      _Pragma("unroll") for (int m = 0; m < 4; m++)                                \
        af[m] = *(const bf16x8*)&As[(wr * 64 + m * 16 + fr) * 64 + kk * 32 + fq * 8]; \
      _Pragma("unroll") for (int n = 0; n < 4; n++)                                \
        bfr[n] = *(const bf16x8*)&Bs[(wc * 64 + n * 16 + fr) * 64 + kk * 32 + fq * 8]; \
      _Pragma("unroll") for (int m = 0; m < 4; m++)                                \
        _Pragma("unroll") for (int n = 0; n < 4; n++)                              \
          acc[m][n] = __builtin_amdgcn_mfma_f32_16x16x32_bf16(af[m], bfr[n], acc[m][n], 0, 0, 0); \
    }                                                                              \
    __syncthreads();                                                               \
  }

// Fused QKV projection: Bt = [Wq^T | Wk^T | Wv^T] as [6144][4096].
__global__ __launch_bounds__(256) void gemm_qkv(const u16* __restrict__ A,
                                                const u16* __restrict__ Bt,
                                                u16* __restrict__ Qb,
                                                u16* __restrict__ Kb,
                                                u16* __restrict__ Vb) {
  const long brow = (long)blockIdx.y * 128, bcol = (long)blockIdx.x * 128;
  GEMM_BODY(A, Bt, HIDDEN)
  u16* dst;
  long nst, cb;
  if (bcol < 4096)      { dst = Qb; nst = 4096; cb = bcol; }
  else if (bcol < 5120) { dst = Kb; nst = 1024; cb = bcol - 4096; }
  else                  { dst = Vb; nst = 1024; cb = bcol - 5120; }
#pragma unroll
  for (int m = 0; m < 4; m++)
#pragma unroll
    for (int j = 0; j < 4; j++) {
      long row = brow + wr * 64 + m * 16 + fq * 4 + j;
#pragma unroll
      for (int n = 0; n < 4; n++)
        dst[row * nst + cb + wc * 64 + n * 16 + fr] = f2bf(acc[m][n][j]);
    }
}

// Output projection: C fp32 [M][N]
__global__ __launch_bounds__(256) void gemm_out(const u16* __restrict__ A,
                                                const u16* __restrict__ Bt,
                                                float* __restrict__ C) {
  const long brow = (long)blockIdx.y * 128, bcol = (long)blockIdx.x * 128;
  GEMM_BODY(A, Bt, HIDDEN)
#pragma unroll
  for (int m = 0; m < 4; m++)
#pragma unroll
    for (int j = 0; j < 4; j++) {
      long row = brow + wr * 64 + m * 16 + fq * 4 + j;
#pragma unroll
      for (int n = 0; n < 4; n++)
        C[row * HIDDEN + bcol + wc * 64 + n * 16 + fr] = acc[m][n][j];
    }
}

// ---------------- flash attention (causal, GQA) ----------------
// EXACT r4 version (120 VGPR, 383us): grid (S/64, NH, B), 4 waves x 16 q-rows,
// T2 swizzled 40KB LDS (4 blocks/CU), T14 depth-2 reg prefetch, T13 defer-max,
// pre-scaled Q, LPT order. WARNING: VGPR cliff at 128 — any edit that pushes
// VGPR_Count past 128 halves occupancy (r5: 136 VGPR -> 576us).

__global__ __launch_bounds__(256) void attn_fwd(const u16* __restrict__ Q,
                                                const u16* __restrict__ K,
                                                const u16* __restrict__ Vt,
                                                const float* __restrict__ amask,
                                                u16* __restrict__ O) {
  const int b = blockIdx.z, h = blockIdx.y;
  const int qi = gridDim.x - 1 - blockIdx.x;   // heavy (high-qb) blocks first (LPT)
  const int qb = qi * 64;
  const int kvh = h >> 2;
  const int t = threadIdx.x, lane = t & 63, w = t >> 6;
  const int fr = lane & 15, fq = lane >> 4;

  __shared__ u16 KlA[64 * 128];       // [key][d],   swizzled, 16KB
  __shared__ u16 VlA[128 * 64];       // [d][key],   swizzled, 16KB
  __shared__ u16 PlA[4][16 * 64];     // per-wave [qrow][key], swizzled, 8KB

  bf16x8 qf[4];
  {
    const int qrow = qb + w * 16 + fr;
    const long qbase = (((long)b * SS + qrow) * NH + h) * HD;
#pragma unroll
    for (int kk = 0; kk < 4; kk++)
      qf[kk] = *(const bf16x8*)&Q[qbase + kk * 32 + fq * 8];
  }

  const u16* Kh = K + (long)b * SS * NKV * HD + (long)kvh * HD;
  const u16* Vh = Vt + ((long)b * NKV + kvh) * (long)HD * SS;
  const float* Mh = amask + (long)b * SS;
  u16* Plw = PlA[w];

  const int kst = t >> 4, kcol = (t & 15) * 8;   // K: 64 rows x 128 cols
  const int vst = t >> 3, vcol = (t & 7) * 8;    // V: 128 rows x 64 cols

  bf16x8 kreg[4], vreg[4];
  auto load_tile = [&](int kv0) {
#pragma unroll
    for (int i = 0; i < 4; i++)
      kreg[i] = *(const bf16x8*)&Kh[(long)(kv0 + kst + i * 16) * (NKV * HD) + kcol];
#pragma unroll
    for (int i = 0; i < 4; i++)
      vreg[i] = *(const bf16x8*)&Vh[(long)(vst + i * 32) * SS + kv0 + vcol];
  };
  auto write_tile = [&]() {
#pragma unroll
    for (int i = 0; i < 4; i++)
      *(bf16x8*)swzp(KlA, kst + i * 16, kcol, 128) = kreg[i];
#pragma unroll
    for (int i = 0; i < 4; i++)
      *(bf16x8*)swzp(VlA, vst + i * 32, vcol, 64) = vreg[i];
  };

  f32x4 oacc[8] = {};
  float mrow[4], lrow[4];
#pragma unroll
  for (int j = 0; j < 4; j++) { mrow[j] = -1e30f; lrow[j] = 0.f; }
  int qr0 = qb + w * 16 + fq * 4;
  const float L2E = 1.4426950408889634f;

  const int ntiles = qi + 1;
  load_tile(0);
  write_tile();
  __syncthreads();
  if (ntiles > 1) load_tile(64);

  for (int kvt = 0; kvt < ntiles; kvt++) {
    const int kv0 = kvt * 64;

    // mask values (issued early; consumed after QK^T)
    float mk[4];
#pragma unroll
    for (int n = 0; n < 4; n++) mk[n] = Mh[kv0 + n * 16 + fr];

    // ---- S = Q K^T ----
    f32x4 sacc[4] = {};
#pragma unroll
    for (int n = 0; n < 4; n++)
#pragma unroll
      for (int kk = 0; kk < 4; kk++) {
        bf16x8 kf = *(const bf16x8*)swzc(KlA, n * 16 + fr, kk * 32 + fq * 8, 128);
        sacc[n] = __builtin_amdgcn_mfma_f32_16x16x32_bf16(qf[kk], kf, sacc[n], 0, 0, 0);
      }

    // ---- mask (Q pre-scaled; in-place in sacc) ----
    const bool diag = (kvt == qi);
#pragma unroll
    for (int n = 0; n < 4; n++) {
      const int key = kv0 + n * 16 + fr;
#pragma unroll
      for (int j = 0; j < 4; j++) {
        float v = sacc[n][j];
        if ((diag && key > qr0 + j) || mk[n] <= 0.f) v = -1e30f;
        sacc[n][j] = v;
      }
    }

    // ---- online softmax with defer-max (T13, THR=8) ----
    float pm[4];
    bool need = false;
#pragma unroll
    for (int j = 0; j < 4; j++) {
      float mx = fmaxf(fmaxf(sacc[0][j], sacc[1][j]), fmaxf(sacc[2][j], sacc[3][j]));
#pragma unroll
      for (int d = 1; d < 16; d <<= 1) mx = fmaxf(mx, __shfl_xor(mx, d, 64));
      pm[j] = mx;
      need = need || (mx > mrow[j] + 8.f);
    }
    if (__any(need)) {
#pragma unroll
      for (int j = 0; j < 4; j++) {
        float mnew = fmaxf(mrow[j], pm[j]);
        float alpha = exp2f((mrow[j] - mnew) * L2E);
        lrow[j] *= alpha;
        mrow[j] = mnew;
#pragma unroll
        for (int no = 0; no < 8; no++) oacc[no][j] *= alpha;
      }
    }
#pragma unroll
    for (int j = 0; j < 4; j++) {
      float sum = 0.f;
#pragma unroll
      for (int n = 0; n < 4; n++) {
        float pv = exp2f((sacc[n][j] - mrow[j]) * L2E);
        sacc[n][j] = pv;
        sum += pv;
      }
#pragma unroll
      for (int d = 1; d < 16; d <<= 1) sum += __shfl_xor(sum, d, 64);
      lrow[j] += sum;
    }

    // ---- P -> LDS (per-wave region; same-wave DS ordering, no barrier) ----
#pragma unroll
    for (int n = 0; n < 4; n++)
#pragma unroll
      for (int j = 0; j < 4; j++)
        *swzp(Plw, fq * 4 + j, n * 16 + fr, 64) = f2bf(sacc[n][j]);

    // ---- O += P V ----
#pragma unroll
    for (int kk = 0; kk < 2; kk++) {
      bf16x8 pf = *(const bf16x8*)swzc(Plw, fr, kk * 32 + fq * 8, 64);
#pragma unroll
      for (int no = 0; no < 8; no++) {
        bf16x8 vf = *(const bf16x8*)swzc(VlA, no * 16 + fr, kk * 32 + fq * 8, 64);
        oacc[no] = __builtin_amdgcn_mfma_f32_16x16x32_bf16(pf, vf, oacc[no], 0, 0, 0);
      }
    }

    __syncthreads();               // all waves done reading Kl/Vl tile t
    if (kvt + 1 < ntiles) {
      write_tile();                // tile t+1 regs -> LDS
      if (kvt + 2 < ntiles) load_tile((kvt + 2) * 64);  // prefetch t+2
      __syncthreads();             // staging visible
    }
  }

  // ---- epilogue ----
#pragma unroll
  for (int j = 0; j < 4; j++) {
    const int row = qb + w * 16 + fq * 4 + j;
    const float inv = 1.0f / lrow[j];
    const long obase = (((long)b * SS + row) * NH + h) * HD;
#pragma unroll
    for (int no = 0; no < 8; no++)
      O[obase + no * 16 + fr] = f2bf(oacc[no][j] * inv);
  }
}

// ---------------- launch ----------------

extern "C" void kernel_launch(void* const* d_in, const int* in_sizes, int n_in,
                              void* d_out, int out_size, void* d_ws, size_t ws_size,
                              hipStream_t stream) {
  const float* hs    = (const float*)d_in[0];
  const float* amask = (const float*)d_in[1];
  const int*   pid   = (const int*)d_in[2];
  const float* Wq    = (const float*)d_in[3];
  const float* Wk    = (const float*)d_in[4];
  const float* Wv    = (const float*)d_in[5];
  const float* Wo    = (const float*)d_in[6];
  float* out = (float*)d_out;

  char* ws = (char*)d_ws;
  const size_t MB = 1024ull * 1024ull;
  u16* Xb    = (u16*)(ws + 0);         // 32MB, later reused as attention output
  u16* Wqkvt = (u16*)(ws + 32 * MB);   // 48MB: [Wq^T|Wk^T|Wv^T] as [6144][4096]
  u16* Wot   = (u16*)(ws + 80 * MB);   // 32MB
  u16* Qb    = (u16*)(ws + 112 * MB);  // 32MB
  u16* Kb    = (u16*)(ws + 144 * MB);  // 8MB
  u16* Vb    = (u16*)(ws + 152 * MB);  // 8MB
  u16* Vtb   = (u16*)(ws + 160 * MB);  // 8MB
  float* st  = (float*)(ws + 168 * MB);// 1MB
  float* ct  = (float*)(ws + 169 * MB);// 1MB
  u16* Ab = Xb;                        // alias: Xb dead after QKV GEMM

  rope_table<<<(MAXPOS * 64) / 256, 256, 0, stream>>>(st, ct);
  conv_bf16<<<(TOK * HIDDEN / 8) / 256, 256, 0, stream>>>(hs, Xb, TOK * HIDDEN / 8);
  conv_transpose<<<dim3(HIDDEN / 64, HIDDEN / 64), 256, 0, stream>>>(Wq, Wqkvt, HIDDEN, HIDDEN);
  conv_transpose<<<dim3(1024 / 64, HIDDEN / 64), 256, 0, stream>>>(Wk, Wqkvt + 4096ull * 4096, HIDDEN, 1024);
  conv_transpose<<<dim3(1024 / 64, HIDDEN / 64), 256, 0, stream>>>(Wv, Wqkvt + 5120ull * 4096, HIDDEN, 1024);
  conv_transpose<<<dim3(HIDDEN / 64, HIDDEN / 64), 256, 0, stream>>>(Wo, Wot, HIDDEN, HIDDEN);

  gemm_qkv<<<dim3(NQKV / 128, TOK / 128), 256, 0, stream>>>(Xb, Wqkvt, Qb, Kb, Vb);

  const float qscale = 0.08838834764831845f;  // 1/sqrt(HD)
  rope_apply<<<(TOK * NH * 64) / 256, 256, 0, stream>>>(Qb, pid, st, ct, NH, TOK * NH * 64, qscale);
  rope_apply<<<(TOK * NKV * 64) / 256, 256, 0, stream>>>(Kb, pid, st, ct, NKV, TOK * NKV * 64, 1.0f);

  vtrans<<<dim3(SS / 64, HD / 64, BB * NKV), 256, 0, stream>>>(Vb, Vtb);

  attn_fwd<<<dim3(SS / 64, NH, BB), 256, 0, stream>>>(Qb, Kb, Vtb, amask, Ab);

  gemm_out<<<dim3(HIDDEN / 128, TOK / 128), 256, 0, stream>>>(Ab, Wot, out);
}